// Round 1
// baseline (2026.834 us; speedup 1.0000x reference)
//
#include <hip/hip_runtime.h>
#include <math.h>

#define DIM 128
#define NEG 0.2f
#define EPS 1e-5f

static __device__ __forceinline__ float leaky(float a) { return a > 0.f ? a : NEG * a; }

// ---------------- K1: h = x@W, plus a_src/a_dst head dots ----------------
__global__ __launch_bounds__(256) void k_gemm(const float* __restrict__ x,
                                              const float* __restrict__ W,
                                              const float* __restrict__ att_s,
                                              const float* __restrict__ att_d,
                                              float* __restrict__ h,
                                              float* __restrict__ asrc,
                                              float* __restrict__ adst, int n) {
    __shared__ float2 Ws[DIM][64];  // Ws[k][l] = {W[k][l], W[k][l+64]} -> 64KB
    for (int idx = threadIdx.x; idx < DIM * 64; idx += 256) {
        int k = idx >> 6, l = idx & 63;
        Ws[k][l] = make_float2(W[k * DIM + l], W[k * DIM + 64 + l]);
    }
    __syncthreads();
    const int lane = threadIdx.x & 63;
    const float as0 = att_s[lane], as1 = att_s[64 + lane];
    const float ad0 = att_d[lane], ad1 = att_d[64 + lane];
    int wave = blockIdx.x * 4 + (threadIdx.x >> 6);
    int nw = gridDim.x * 4;
    for (int r0 = wave * 4; r0 < n; r0 += nw * 4) {
        int rows[4];
#pragma unroll
        for (int rr = 0; rr < 4; ++rr) rows[rr] = min(r0 + rr, n - 1);
        float acc[4][2] = {{0.f, 0.f}, {0.f, 0.f}, {0.f, 0.f}, {0.f, 0.f}};
        for (int k4 = 0; k4 < DIM; k4 += 4) {
            float4 xv[4];
#pragma unroll
            for (int rr = 0; rr < 4; ++rr)
                xv[rr] = *(const float4*)(x + (size_t)rows[rr] * DIM + k4);
#pragma unroll
            for (int kk = 0; kk < 4; ++kk) {
                float2 w = Ws[k4 + kk][lane];
#pragma unroll
                for (int rr = 0; rr < 4; ++rr) {
                    float xk = ((const float*)&xv[rr])[kk];
                    acc[rr][0] = fmaf(xk, w.x, acc[rr][0]);
                    acc[rr][1] = fmaf(xk, w.y, acc[rr][1]);
                }
            }
        }
#pragma unroll
        for (int rr = 0; rr < 4; ++rr) {
            int r = r0 + rr;
            if (r >= n) break;
            float h0 = acc[rr][0], h1 = acc[rr][1];
            float p0 = h0 * as0, p1 = h1 * as1;
            float q0 = h0 * ad0, q1 = h1 * ad1;
#pragma unroll
            for (int m = 1; m < 32; m <<= 1) {
                p0 += __shfl_xor(p0, m);
                p1 += __shfl_xor(p1, m);
                q0 += __shfl_xor(q0, m);
                q1 += __shfl_xor(q1, m);
            }
            h[(size_t)r * DIM + lane] = h0;
            h[(size_t)r * DIM + 64 + lane] = h1;
            if (lane == 0) {
                asrc[r * 4 + 0] = p0; asrc[r * 4 + 2] = p1;
                adst[r * 4 + 0] = q0; adst[r * 4 + 2] = q1;
            } else if (lane == 32) {
                asrc[r * 4 + 1] = p0; asrc[r * 4 + 3] = p1;
                adst[r * 4 + 1] = q0; adst[r * 4 + 3] = q1;
            }
        }
    }
}

// ---------------- K2: init deg=1 (self loop) and zero BN stats ----------------
__global__ void k_init(int* __restrict__ deg, float* __restrict__ stats, int n) {
    int t = blockIdx.x * blockDim.x + threadIdx.x;
    if (t < n) deg[t] = 1;
    if (t < 256) stats[t] = 0.f;
}

// ---------------- K3: histogram of dst ----------------
__global__ void k_hist(const int* __restrict__ dst, int* __restrict__ deg, int E) {
    int t = blockIdx.x * blockDim.x + threadIdx.x;
    if (t < E) atomicAdd(&deg[dst[t]], 1);
}

// ---------------- K4: single-block exclusive scan over deg ----------------
__global__ __launch_bounds__(1024) void k_scan(const int* __restrict__ deg,
                                               int* __restrict__ row_start,
                                               int* __restrict__ cursor, int n) {
    __shared__ int lds[1024];
    int tid = threadIdx.x;
    int chunk = (n + 1023) >> 10;
    int beg = tid * chunk, end = min(beg + chunk, n);
    int s = 0;
    for (int i = beg; i < end; ++i) s += deg[i];
    lds[tid] = s;
    __syncthreads();
    int v = s;
    for (int ofs = 1; ofs < 1024; ofs <<= 1) {
        int t = (tid >= ofs) ? lds[tid - ofs] : 0;
        __syncthreads();
        v += t;
        lds[tid] = v;
        __syncthreads();
    }
    int excl = v - s;
    for (int i = beg; i < end; ++i) {
        row_start[i] = excl;
        cursor[i] = excl;
        excl += deg[i];
    }
    if (tid == 1023) row_start[n] = v;  // total = E + n
}

// ---------------- K5: scatter edges (and self loops) into CSR ----------------
__global__ void k_scatter(const int* __restrict__ src, const int* __restrict__ dst,
                          int* __restrict__ cursor, int* __restrict__ csr, int E, int n) {
    int t = blockIdx.x * blockDim.x + threadIdx.x;
    if (t < E) {
        int d = dst[t];
        int slot = atomicAdd(&cursor[d], 1);
        csr[slot] = src[t];
    } else if (t < E + n) {
        int i = t - E;
        int slot = atomicAdd(&cursor[i], 1);
        csr[slot] = i;
    }
}

// ---------------- K6: per-dst-node online-softmax aggregation + residual + bias
//                      + BN partial stats. One wave per node. ----------------
__global__ __launch_bounds__(256) void k_agg(const float* __restrict__ h,
                                             const float* __restrict__ asrc,
                                             const float* __restrict__ adst,
                                             const int* __restrict__ row_start,
                                             const int* __restrict__ csr,
                                             const float* __restrict__ prev,
                                             const float* __restrict__ bias,
                                             float* __restrict__ ypre,
                                             float* __restrict__ stats, int n) {
    const int lane = threadIdx.x & 63;
    const int hh = lane >> 5;  // head selector for channel `lane` (0/1); +2 for lane+64
    int wave = blockIdx.x * 4 + (threadIdx.x >> 6);
    int nw = gridDim.x * 4;
    const float b0 = bias[lane], b1 = bias[64 + lane];
    float bsum0 = 0.f, bsq0 = 0.f, bsum1 = 0.f, bsq1 = 0.f;
    for (int i0 = wave; i0 < n; i0 += nw) {
        int i = __builtin_amdgcn_readfirstlane(i0);
        int e0 = row_start[i], e1 = row_start[i + 1];
        float adx0 = adst[i * 4 + hh];
        float adx1 = adst[i * 4 + 2 + hh];
        float m0 = -1e30f, m1 = -1e30f, s0 = 0.f, s1 = 0.f, acc0 = 0.f, acc1 = 0.f;
        for (int e = e0; e < e1; ++e) {
            int j = csr[e];
            float al0 = leaky(asrc[j * 4 + hh] + adx0);
            float al1 = leaky(asrc[j * 4 + 2 + hh] + adx1);
            float h0 = h[(size_t)j * DIM + lane];
            float h1 = h[(size_t)j * DIM + 64 + lane];
            float mn0 = fmaxf(m0, al0);
            float sc0 = __expf(m0 - mn0);
            float p0 = __expf(al0 - mn0);
            s0 = s0 * sc0 + p0;
            acc0 = fmaf(acc0, sc0, p0 * h0);
            m0 = mn0;
            float mn1 = fmaxf(m1, al1);
            float sc1 = __expf(m1 - mn1);
            float p1 = __expf(al1 - mn1);
            s1 = s1 * sc1 + p1;
            acc1 = fmaf(acc1, sc1, p1 * h1);
            m1 = mn1;
        }
        float o0 = acc0 / s0 + b0 + prev[(size_t)i * DIM + lane];
        float o1 = acc1 / s1 + b1 + prev[(size_t)i * DIM + 64 + lane];
        ypre[(size_t)i * DIM + lane] = o0;
        ypre[(size_t)i * DIM + 64 + lane] = o1;
        bsum0 += o0; bsq0 = fmaf(o0, o0, bsq0);
        bsum1 += o1; bsq1 = fmaf(o1, o1, bsq1);
    }
    __shared__ float red[4][256];
    red[0][threadIdx.x] = bsum0;
    red[1][threadIdx.x] = bsq0;
    red[2][threadIdx.x] = bsum1;
    red[3][threadIdx.x] = bsq1;
    __syncthreads();
    if (threadIdx.x < 64) {
        int t = threadIdx.x;
        float v0 = red[0][t] + red[0][t + 64] + red[0][t + 128] + red[0][t + 192];
        float v1 = red[1][t] + red[1][t + 64] + red[1][t + 128] + red[1][t + 192];
        float v2 = red[2][t] + red[2][t + 64] + red[2][t + 128] + red[2][t + 192];
        float v3 = red[3][t] + red[3][t + 64] + red[3][t + 128] + red[3][t + 192];
        atomicAdd(&stats[t], v0);        // sum, channel t
        atomicAdd(&stats[64 + t], v2);   // sum, channel 64+t
        atomicAdd(&stats[128 + t], v1);  // sumsq, channel t
        atomicAdd(&stats[192 + t], v3);  // sumsq, channel 64+t
    }
}

// ---------------- K7: finalize BN scale/shift ----------------
__global__ void k_bnfin(const float* __restrict__ stats, const float* __restrict__ gamma,
                        const float* __restrict__ beta, float* __restrict__ AB, int n) {
    int c = threadIdx.x;  // 128 threads
    float fn = (float)n;
    float mean = stats[c] / fn;
    float var = stats[128 + c] / fn - mean * mean;
    float a = gamma[c] * rsqrtf(var + EPS);
    AB[c] = a;
    AB[128 + c] = beta[c] - mean * a;
}

// ---------------- K8: y = relu(y*A + B), in place, float4 ----------------
__global__ __launch_bounds__(256) void k_final(float* __restrict__ y,
                                               const float* __restrict__ AB, int total4) {
    int t0 = blockIdx.x * blockDim.x + threadIdx.x;
    int stride = gridDim.x * blockDim.x;
    for (int t = t0; t < total4; t += stride) {
        float4 v = ((float4*)y)[t];
        int c0 = (t * 4) & 127;
        v.x = fmaf(v.x, AB[c0 + 0], AB[128 + c0 + 0]);
        v.y = fmaf(v.y, AB[c0 + 1], AB[128 + c0 + 1]);
        v.z = fmaf(v.z, AB[c0 + 2], AB[128 + c0 + 2]);
        v.w = fmaf(v.w, AB[c0 + 3], AB[128 + c0 + 3]);
        v.x = v.x > 0.f ? v.x : 0.f;
        v.y = v.y > 0.f ? v.y : 0.f;
        v.z = v.z > 0.f ? v.z : 0.f;
        v.w = v.w > 0.f ? v.w : 0.f;
        ((float4*)y)[t] = v;
    }
}

extern "C" void kernel_launch(void* const* d_in, const int* in_sizes, int n_in,
                              void* d_out, int out_size, void* d_ws, size_t ws_size,
                              hipStream_t stream) {
    const float* prev  = (const float*)d_in[0];
    const float* x     = (const float*)d_in[1];
    const int*   ei    = (const int*)d_in[2];
    const float* W     = (const float*)d_in[3];
    const float* att_s = (const float*)d_in[4];
    const float* att_d = (const float*)d_in[5];
    const float* bias  = (const float*)d_in[6];
    const float* gamma = (const float*)d_in[7];
    const float* beta  = (const float*)d_in[8];
    const int n = in_sizes[0] / DIM;
    const int E = in_sizes[2] / 2;
    const int* src = ei;
    const int* dst = ei + E;

    char* p = (char*)d_ws;
    auto alloc = [&](size_t bytes) {
        void* q = (void*)p;
        p += (bytes + 255) & ~(size_t)255;
        return q;
    };
    float* h         = (float*)alloc((size_t)n * DIM * 4);
    float* asrc      = (float*)alloc((size_t)n * 4 * 4);
    float* adst      = (float*)alloc((size_t)n * 4 * 4);
    int*   deg       = (int*)alloc((size_t)(n + 1) * 4);
    int*   row_start = (int*)alloc((size_t)(n + 1) * 4);
    int*   cursor    = (int*)alloc((size_t)(n + 1) * 4);
    int*   csr       = (int*)alloc((size_t)(E + n) * 4);
    float* stats     = (float*)alloc(256 * 4);
    float* AB        = (float*)alloc(256 * 4);
    float* yout      = (float*)d_out;

    k_init<<<dim3((n + 255) / 256), dim3(256), 0, stream>>>(deg, stats, n);
    k_gemm<<<dim3(512), dim3(256), 0, stream>>>(x, W, att_s, att_d, h, asrc, adst, n);
    k_hist<<<dim3((E + 255) / 256), dim3(256), 0, stream>>>(dst, deg, E);
    k_scan<<<dim3(1), dim3(1024), 0, stream>>>(deg, row_start, cursor, n);
    k_scatter<<<dim3((E + n + 255) / 256), dim3(256), 0, stream>>>(src, dst, cursor, csr, E, n);
    k_agg<<<dim3(2048), dim3(256), 0, stream>>>(h, asrc, adst, row_start, csr, prev, bias, yout, stats, n);
    k_bnfin<<<dim3(1), dim3(128), 0, stream>>>(stats, gamma, beta, AB, n);
    int total4 = n * DIM / 4;
    k_final<<<dim3(2048), dim3(256), 0, stream>>>(yout, AB, total4);
}